// Round 12
// baseline (598.733 us; speedup 1.0000x reference)
//
#include <hip/hip_runtime.h>
#include <hip/hip_fp16.h>

// GCN forward, CSR-gather. Layer1: fused balanced-pair-zip fp16 gather +
// fp32 GEMM (R11, proven). Layer2 SPLIT (resolves the MFMA-vs-occupancy
// conflict of R9/R10): standalone fp16 gather (R0 structure: 1 wave/node,
// every wave always gathering -> no GEMM bubble) writes fp16 agg2; then a
// pure MFMA GEMM+pool kernel (wave owns 64 nodes = 4 M=16 tiles, B-fragment
// reuse x4, A direct from global 16B/lane, 2-term hi/lo B for precision --
// all fragment layouts + pool epilogue verified in R10). Fusion's round-trip
// saving at fp16 is only ~9us; the GEMM bubble it bought was ~54us.

#define NN 100000
#define NE 1600000
#define NG 512
#define NBLK ((NN + 1023) / 1024)   // 98 scan blocks
#define NTASK2 1563                  // ceil(NN/64) mm2pool tasks
#define NNPAD 100032                 // NTASK2*64 (agg2 padded rows)

typedef float v2f __attribute__((ext_vector_type(2)));
typedef _Float16 half8 __attribute__((ext_vector_type(8)));
typedef float f32x4 __attribute__((ext_vector_type(4)));

// ---------------- CSR build (counting sort by dst) ----------------

__global__ void k_hist(const int* __restrict__ dst, int* cnt, int e) {
    int i = blockIdx.x * blockDim.x + threadIdx.x;
    if (i < e) atomicAdd(&cnt[dst[i]], 1);
}

__global__ void k_prep(const int* __restrict__ cnt, float* __restrict__ dinv,
                       float* __restrict__ gmax) {
    int i = blockIdx.x * blockDim.x + threadIdx.x;
    if (i < NN) dinv[i] = rsqrtf((float)cnt[i] + 1.0f);
    if (i < NG * 256) gmax[i] = 0.0f;
}

// x [NN][78] fp32 -> xh fp16
__global__ void k_cvt_x(const float* __restrict__ x, __half* __restrict__ xh) {
    int i = blockIdx.x * blockDim.x + threadIdx.x;
    if (i < NN * 39) {
        float2 v = ((const float2*)x)[i];
        ((__half2*)xh)[i] = __floats2half2_rn(v.x, v.y);
    }
}

// W2 [128][256] fp32 -> fragment-ordered fp16 hi/lo:
// idx = ((nt*4+ks)*64+lane)*8+j ; n = nt*16+(lane&15) ; k = ks*32+(lane>>4)*8+j
__global__ void k_pack_w2(const float* __restrict__ W, __half* __restrict__ Wh,
                          __half* __restrict__ Wl) {
    int i = blockIdx.x * blockDim.x + threadIdx.x;
    if (i >= 32768) return;
    int j = i & 7, lane = (i >> 3) & 63, ks = (i >> 9) & 3, nt = i >> 11;
    int n = nt * 16 + (lane & 15);
    int k = ks * 32 + ((lane >> 4) << 3) + j;
    float v = W[k * 256 + n];
    __half hi = __float2half_rn(v);
    Wh[i] = hi;
    Wl[i] = __float2half_rn(v - __half2float(hi));
}

__global__ __launch_bounds__(256) void k_bsum(const int* __restrict__ cnt, int* __restrict__ bsum) {
    __shared__ int s[256];
    int b = blockIdx.x, t = threadIdx.x;
    int base = b * 1024 + t * 4;
    int v = 0;
#pragma unroll
    for (int j = 0; j < 4; j++) { int i = base + j; if (i < NN) v += cnt[i]; }
    s[t] = v; __syncthreads();
    for (int off = 128; off > 0; off >>= 1) {
        if (t < off) s[t] += s[t + off];
        __syncthreads();
    }
    if (t == 0) bsum[b] = s[0];
}

__global__ __launch_bounds__(128) void k_scan_bsum(int* bsum, int* row_ptr) {
    __shared__ int s[128];
    int t = threadIdx.x;
    int v = (t < NBLK) ? bsum[t] : 0;
    s[t] = v; __syncthreads();
    for (int off = 1; off < 128; off <<= 1) {
        int u = (t >= off) ? s[t - off] : 0;
        __syncthreads();
        s[t] += u;
        __syncthreads();
    }
    if (t < NBLK) bsum[t] = s[t] - v;
    if (t == 0) row_ptr[NN] = NE;
}

__global__ __launch_bounds__(256) void k_scan_blocks(const int* __restrict__ cnt,
    const int* __restrict__ bsum, int* __restrict__ row_ptr, int* __restrict__ cursor) {
    __shared__ int s[256];
    int b = blockIdx.x, t = threadIdx.x;
    int base = b * 1024 + t * 4;
    int v[4]; int sum = 0;
#pragma unroll
    for (int j = 0; j < 4; j++) { int i = base + j; v[j] = (i < NN) ? cnt[i] : 0; sum += v[j]; }
    s[t] = sum; __syncthreads();
    for (int off = 1; off < 256; off <<= 1) {
        int u = (t >= off) ? s[t - off] : 0;
        __syncthreads();
        s[t] += u;
        __syncthreads();
    }
    int excl = s[t] - sum + bsum[b];
#pragma unroll
    for (int j = 0; j < 4; j++) {
        int i = base + j;
        if (i < NN) { row_ptr[i] = excl; cursor[i] = excl; excl += v[j]; }
    }
}

__global__ void k_fillslots(const int* __restrict__ src, const int* __restrict__ dst,
    const float* __restrict__ dinv, int* cursor, int2* __restrict__ es, int e) {
    int i = blockIdx.x * blockDim.x + threadIdx.x;
    if (i >= e) return;
    int s = src[i], d = dst[i];
    int pos = atomicAdd(&cursor[d], 1);
    es[pos] = make_int2(s, __float_as_int(dinv[s] * dinv[d]));
}

// ---------------- fused1: balanced pair-zip fp16 gather78 + fp32 gemm1 -> fp16 h1 ----------------
__global__ __launch_bounds__(256) void k_fused1(const __half* __restrict__ x,
    const int* __restrict__ rp, const int2* __restrict__ es,
    const float* __restrict__ dinv, const float* __restrict__ W,
    const float* __restrict__ bias, __half* __restrict__ out) {
    __shared__ float As[4][8][80];   // 10 KB
    int tid = threadIdx.x;
    int wv = tid >> 6, l = tid & 63;
    int task = __builtin_amdgcn_readfirstlane(blockIdx.x * 4 + wv);  // 12500 tasks
    int n0 = task * 8;
    if (n0 >= NN) return;

    // degree-balanced pairing: sort local indices by degree (uniform values)
    int deg[8], idx[8];
    {
        int e0 = rp[n0], ei;
#pragma unroll
        for (int i = 0; i < 8; i++) {
            ei = rp[n0 + i + 1];
            deg[i] = ei - e0; e0 = ei; idx[i] = i;
        }
    }
#pragma unroll
    for (int i = 1; i < 8; i++) {
        int dv = deg[i], iv = idx[i], j = i - 1;
        while (j >= 0 && deg[j] > dv) {
            deg[j + 1] = deg[j]; idx[j + 1] = idx[j]; j--;
        }
        deg[j + 1] = dv; idx[j + 1] = iv;
    }

    if (l < 39) {
        for (int pi = 0; pi < 4; pi++) {
            int iA = idx[2 * pi], iB = idx[2 * pi + 1];
            int nA = n0 + iA, nB = n0 + iB;
            float diA = dinv[nA], swA = diA * diA;
            float diB = dinv[nB], swB = diB * diB;
            float2 aA = __half22float2(((const __half2*)(x + (size_t)nA * 78))[l]);
            float2 aB = __half22float2(((const __half2*)(x + (size_t)nB * 78))[l]);
            aA.x *= swA; aA.y *= swA;
            aB.x *= swB; aB.y *= swB;
            int eA = rp[nA], eA1 = rp[nA + 1];
            int eB = rp[nB], eB1 = rp[nB + 1];
            int cA = (eA1 - eA) >> 3, cB = (eB1 - eB) >> 3;
            while (cA > 0 || cB > 0) {
                bool dA = (cA > 0), dB = (cB > 0);
                int2 esA[8], esB[8];
                __half2 vA[8], vB[8];
                if (dA) {
#pragma unroll
                    for (int j = 0; j < 8; j++) esA[j] = es[eA + j];
                }
                if (dB) {
#pragma unroll
                    for (int j = 0; j < 8; j++) esB[j] = es[eB + j];
                }
                if (dA) {
#pragma unroll
                    for (int j = 0; j < 8; j++)
                        vA[j] = ((const __half2*)(x + (size_t)esA[j].x * 78))[l];
                }
                if (dB) {
#pragma unroll
                    for (int j = 0; j < 8; j++)
                        vB[j] = ((const __half2*)(x + (size_t)esB[j].x * 78))[l];
                }
                if (dA) {
#pragma unroll
                    for (int j = 0; j < 8; j++) {
                        float w = __int_as_float(esA[j].y);
                        float2 v = __half22float2(vA[j]);
                        aA.x += v.x * w; aA.y += v.y * w;
                    }
                    eA += 8; cA--;
                }
                if (dB) {
#pragma unroll
                    for (int j = 0; j < 8; j++) {
                        float w = __int_as_float(esB[j].y);
                        float2 v = __half22float2(vB[j]);
                        aB.x += v.x * w; aB.y += v.y * w;
                    }
                    eB += 8; cB--;
                }
            }
            while (eA < eA1 && eB < eB1) {
                int2 pA = es[eA], pB = es[eB];
                float2 vA2 = __half22float2(((const __half2*)(x + (size_t)pA.x * 78))[l]);
                float2 vB2 = __half22float2(((const __half2*)(x + (size_t)pB.x * 78))[l]);
                float wA = __int_as_float(pA.y), wB = __int_as_float(pB.y);
                aA.x += vA2.x * wA; aA.y += vA2.y * wA;
                aB.x += vB2.x * wB; aB.y += vB2.y * wB;
                eA++; eB++;
            }
            for (; eA < eA1; eA++) {
                int2 p = es[eA];
                float w = __int_as_float(p.y);
                float2 v = __half22float2(((const __half2*)(x + (size_t)p.x * 78))[l]);
                aA.x += v.x * w; aA.y += v.y * w;
            }
            for (; eB < eB1; eB++) {
                int2 p = es[eB];
                float w = __int_as_float(p.y);
                float2 v = __half22float2(((const __half2*)(x + (size_t)p.x * 78))[l]);
                aB.x += v.x * w; aB.y += v.y * w;
            }
            *(float2*)&As[wv][iA][2 * l] = aA;
            *(float2*)&As[wv][iB][2 * l] = aB;
        }
    }
    // same-wave producer/consumer: no barrier needed.

    int f0 = l * 2;
    float2 acc[8];
#pragma unroll
    for (int i = 0; i < 8; i++) acc[i] = make_float2(0.f, 0.f);

    for (int k = 0; k < 76; k += 4) {
        float2 w0 = *(const float2*)&W[(k + 0) * 128 + f0];
        float2 w1 = *(const float2*)&W[(k + 1) * 128 + f0];
        float2 w2 = *(const float2*)&W[(k + 2) * 128 + f0];
        float2 w3 = *(const float2*)&W[(k + 3) * 128 + f0];
#pragma unroll
        for (int i = 0; i < 8; i++) {
            float4 a = *(const float4*)&As[wv][i][k];
            acc[i].x += a.x * w0.x + a.y * w1.x + a.z * w2.x + a.w * w3.x;
            acc[i].y += a.x * w0.y + a.y * w1.y + a.z * w2.y + a.w * w3.y;
        }
    }
    {   // rows 76,77
        float2 w0 = *(const float2*)&W[76 * 128 + f0];
        float2 w1 = *(const float2*)&W[77 * 128 + f0];
#pragma unroll
        for (int i = 0; i < 8; i++) {
            float2 a = *(const float2*)&As[wv][i][76];
            acc[i].x += a.x * w0.x + a.y * w1.x;
            acc[i].y += a.x * w0.y + a.y * w1.y;
        }
    }
    float2 bv = *(const float2*)&bias[f0];
#pragma unroll
    for (int i = 0; i < 8; i++) {
        float ox = fmaxf(acc[i].x + bv.x, 0.f);
        float oy = fmaxf(acc[i].y + bv.y, 0.f);
        *(__half2*)&out[(size_t)(n0 + i) * 128 + f0] = __floats2half2_rn(ox, oy);
    }
}

// ---------------- gather128h: standalone fp16 gather (R0 structure) ----------------
// One wave per node; 64 lanes x half2 (4B). 8-deep pipelined edge loop.
// Every resident wave gathers 100% of the time. Writes fp16 agg2.
__global__ __launch_bounds__(256) void k_gather128h(const __half* __restrict__ h,
    const int* __restrict__ rp, const int2* __restrict__ es,
    const float* __restrict__ dinv, __half* __restrict__ agg) {
    int n = blockIdx.x * 4 + (threadIdx.x >> 6);
    int l = threadIdx.x & 63;
    float di = dinv[n], sw = di * di;
    float2 a = __half22float2(((const __half2*)(h + (size_t)n * 128))[l]);
    a.x *= sw; a.y *= sw;
    int e = rp[n], e1 = rp[n + 1];
    int nf = (e1 - e) >> 3;
    if (nf > 0) {
        int2 cur[8];
#pragma unroll
        for (int j = 0; j < 8; j++) cur[j] = es[e + j];
        for (int b = 1; ; b++) {
            __half2 v[8];
#pragma unroll
            for (int j = 0; j < 8; j++)
                v[j] = ((const __half2*)(h + (size_t)cur[j].x * 128))[l];
            e += 8;
            bool more = (b < nf);
            int2 nxt[8];
            if (more) {
#pragma unroll
                for (int j = 0; j < 8; j++) nxt[j] = es[e + j];
            }
#pragma unroll
            for (int j = 0; j < 8; j++) {
                float w = __int_as_float(cur[j].y);
                float2 vv = __half22float2(v[j]);
                a.x += vv.x * w; a.y += vv.y * w;
            }
            if (!more) break;
#pragma unroll
            for (int j = 0; j < 8; j++) cur[j] = nxt[j];
        }
    }
    for (; e < e1; e++) {
        int2 p = es[e];
        float w = __int_as_float(p.y);
        float2 v = __half22float2(((const __half2*)(h + (size_t)p.x * 128))[l]);
        a.x += v.x * w; a.y += v.y * w;
    }
    ((__half2*)(agg + (size_t)n * 128))[l] = __floats2half2_rn(a.x, a.y);
}

// ---------------- mm2pool: MFMA gemm2 + pool (standalone) ----------------
// 4 waves/block; wave owns 64 nodes (4 M=16 tiles -> B-fragment reuse x4).
// A fragments direct from global agg2 (16B/lane, coalesced; agg2 padded to
// NNPAD rows so last task reads in-bounds). B = W2 hi/lo fragment-packed
// (L2-resident), 2-term MFMA. Pool epilogue verified in R10.
__global__ __launch_bounds__(256) void k_mm2pool(const __half* __restrict__ A,
    const __half* __restrict__ W2h, const __half* __restrict__ W2l,
    const float* __restrict__ bias, const int* __restrict__ batch,
    unsigned* __restrict__ gmax) {
    int tid = threadIdx.x;
    int wv = tid >> 6, l = tid & 63;
    int task = __builtin_amdgcn_readfirstlane(blockIdx.x * 4 + wv);  // 1563 tasks
    if (task >= NTASK2) return;
    int n0 = task * 64;
    int am = l & 15;                   // A row within tile / C col within ntile
    int row4 = (l >> 4) << 2;          // C rows this lane holds: row4..row4+3
    int kb = (l >> 4) << 3;            // k sub-offset within 32-chunk

    half8 ah[4][4];
#pragma unroll
    for (int t = 0; t < 4; t++)
#pragma unroll
        for (int ks = 0; ks < 4; ks++)
            ah[t][ks] = *(const half8*)&A[(size_t)(n0 + t * 16 + am) * 128 + ks * 32 + kb];

    for (int hh = 0; hh < 2; hh++) {
#pragma unroll
        for (int nt = 0; nt < 8; nt++) {
            f32x4 acc[4];
#pragma unroll
            for (int t = 0; t < 4; t++) acc[t] = (f32x4)(0.f);
#pragma unroll
            for (int ks = 0; ks < 4; ks++) {
                int fi = ((((hh * 8 + nt) * 4 + ks) * 64) + l) * 8;
                half8 bh = *(const half8*)&W2h[fi];
                half8 bl = *(const half8*)&W2l[fi];
#pragma unroll
                for (int t = 0; t < 4; t++) {
                    acc[t] = __builtin_amdgcn_mfma_f32_16x16x32_f16(ah[t][ks], bh, acc[t], 0, 0, 0);
                    acc[t] = __builtin_amdgcn_mfma_f32_16x16x32_f16(ah[t][ks], bl, acc[t], 0, 0, 0);
                }
            }
            int ncol = (hh * 8 + nt) * 16 + am;
            float bv = bias[ncol];
            int curg = -1;
            float m = 0.f;
#pragma unroll
            for (int t = 0; t < 4; t++) {
#pragma unroll
                for (int r = 0; r < 4; r++) {
                    int node = n0 + t * 16 + row4 + r;
                    if (node < NN) {
                        int g = batch[node];
                        float v = fmaxf(acc[t][r] + bv, 0.f);
                        if (g != curg) {
                            if (curg >= 0)
                                atomicMax(&gmax[(size_t)curg * 256 + ncol], __float_as_uint(m));
                            curg = g; m = v;
                        } else {
                            m = fmaxf(m, v);
                        }
                    }
                }
            }
            if (curg >= 0)
                atomicMax(&gmax[(size_t)curg * 256 + ncol], __float_as_uint(m));
        }
    }
}

// ---------------- MLP head ----------------

__global__ __launch_bounds__(256) void k_gemm3(const float* __restrict__ A,
    const float* __restrict__ W, const float* __restrict__ bias,
    float* __restrict__ out) {
    __shared__ float rs[8][256];   // 8 KB
    int b = blockIdx.x, tid = threadIdx.x;    // 64 blocks
#pragma unroll
    for (int g = 0; g < 8; g++) rs[g][tid] = A[(b * 8 + g) * 256 + tid];
    __syncthreads();
    float acc[8][4];
#pragma unroll
    for (int g = 0; g < 8; g++)
#pragma unroll
        for (int j = 0; j < 4; j++) acc[g][j] = 0.f;
    for (int k = 0; k < 256; k++) {
        float w0 = W[k * 1024 + tid];
        float w1 = W[k * 1024 + tid + 256];
        float w2 = W[k * 1024 + tid + 512];
        float w3 = W[k * 1024 + tid + 768];
#pragma unroll
        for (int g = 0; g < 8; g++) {
            float a = rs[g][k];
            acc[g][0] += a * w0; acc[g][1] += a * w1;
            acc[g][2] += a * w2; acc[g][3] += a * w3;
        }
    }
#pragma unroll
    for (int g = 0; g < 8; g++)
#pragma unroll
        for (int j = 0; j < 4; j++) {
            int f = tid + j * 256;
            out[(b * 8 + g) * 1024 + f] = fmaxf(acc[g][j] + bias[f], 0.0f);
        }
}

__global__ __launch_bounds__(128) void k_gemm4(const float* __restrict__ A,
    const float* __restrict__ W, const float* __restrict__ bias,
    float* __restrict__ out) {
    __shared__ float rs[4][1024];   // 16 KB
    int b = blockIdx.x, tid = threadIdx.x;    // 128 blocks
    for (int i = tid; i < 4096; i += 128) rs[i >> 10][i & 1023] = A[b * 4096 + i];
    __syncthreads();
    float acc[4] = {0.f, 0.f, 0.f, 0.f};
    for (int k = 0; k < 1024; k++) {
        float wv = W[k * 128 + tid];
#pragma unroll
        for (int g = 0; g < 4; g++) acc[g] += rs[g][k] * wv;
    }
#pragma unroll
    for (int g = 0; g < 4; g++)
        out[(b * 4 + g) * 128 + tid] = acc[g] + bias[tid];
}

extern "C" void kernel_launch(void* const* d_in, const int* in_sizes, int n_in,
                              void* d_out, int out_size, void* d_ws, size_t ws_size,
                              hipStream_t stream) {
    const float* x    = (const float*)d_in[0];
    const int*   ei   = (const int*)d_in[1];
    const int*   batch= (const int*)d_in[2];
    const float* W1   = (const float*)d_in[3];
    const float* b1   = (const float*)d_in[4];
    const float* W2   = (const float*)d_in[5];
    const float* b2   = (const float*)d_in[6];
    const float* Wg1  = (const float*)d_in[7];
    const float* bg1  = (const float*)d_in[8];
    const float* Wg2  = (const float*)d_in[9];
    const float* bg2  = (const float*)d_in[10];
    const int* src = ei;
    const int* dst = ei + NE;

    char* w8 = (char*)d_ws;
    int*   cnt     = (int*)w8;                 w8 += (size_t)NN * 4;
    int*   row_ptr = (int*)w8;                 w8 += (size_t)(NN + 4) * 4;
    int*   cursor  = (int*)w8;                 w8 += (size_t)NN * 4;
    int*   bsum    = (int*)w8;                 w8 += 128 * 4;
    int2*  es      = (int2*)w8;                w8 += (size_t)NE * 8;
    float* dinv    = (float*)w8;               w8 += (size_t)NN * 4;
    __half* xh     = (__half*)w8;              w8 += (size_t)NN * 78 * 2;
    __half* h1     = (__half*)w8;              w8 += (size_t)NN * 128 * 2;
    __half* agg2   = (__half*)w8;              w8 += (size_t)NNPAD * 128 * 2;
    __half* w2h    = (__half*)w8;              w8 += 32768 * 2;
    __half* w2l    = (__half*)w8;              w8 += 32768 * 2;
    unsigned* gmax = (unsigned*)w8;            w8 += (size_t)NG * 256 * 4;
    float* g1      = (float*)w8;               w8 += (size_t)NG * 1024 * 4;

    // CSR build + conversions
    hipMemsetAsync(cnt, 0, (size_t)NN * 4, stream);
    k_hist<<<(NE + 255) / 256, 256, 0, stream>>>(dst, cnt, NE);
    k_cvt_x<<<(NN * 39 + 255) / 256, 256, 0, stream>>>(x, xh);
    k_pack_w2<<<128, 256, 0, stream>>>(W2, w2h, w2l);
    k_prep<<<(NG * 256 + 255) / 256, 256, 0, stream>>>(cnt, dinv, (float*)gmax);
    k_bsum<<<NBLK, 256, 0, stream>>>(cnt, bsum);
    k_scan_bsum<<<1, 128, 0, stream>>>(bsum, row_ptr);
    k_scan_blocks<<<NBLK, 256, 0, stream>>>(cnt, bsum, row_ptr, cursor);
    k_fillslots<<<(NE + 255) / 256, 256, 0, stream>>>(src, dst, dinv, cursor, es, NE);

    // layer 1 (fused balanced pair-zip fp16 gather + fp32 gemm + relu -> fp16 h1)
    k_fused1<<<NN / 32, 256, 0, stream>>>(xh, row_ptr, es, dinv, W1, b1, h1);

    // layer 2 split: standalone fp16 gather -> agg2, then MFMA gemm + pool
    k_gather128h<<<NN / 4, 256, 0, stream>>>(h1, row_ptr, es, dinv, agg2);
    k_mm2pool<<<(NTASK2 + 3) / 4, 256, 0, stream>>>(agg2, w2h, w2l, b2, batch, gmax);

    // MLP head
    k_gemm3<<<NG / 8, 256, 0, stream>>>((const float*)gmax, Wg1, bg1, g1);
    k_gemm4<<<NG / 4, 128, 0, stream>>>(g1, Wg2, bg2, (float*)d_out);
}

// Round 14
// 571.696 us; speedup vs baseline: 1.0473x; 1.0473x over previous
//
#include <hip/hip_runtime.h>
#include <hip/hip_fp16.h>

// GCN forward, CSR-gather, fused gather+GEMM (R11 structure: balanced
// pair-zip, 4 waves/block, 8 nodes/wave, fp16 gather traffic, VGPR-lean).
// NEW: one __syncthreads() between gather and GEMM phases -- the block's 4
// waves then execute the IDENTICAL GEMM instruction stream in lockstep, so
// waves 2-4 hit L1 on wave 1's W fills (GEMM phase was L2-BW-bound: 12500
// waves x 131KB W2 = 1.6GB L2). Cost: max-of-4 gather variance (~9us).
// Also: k_prep folded into k_bsum/k_cvt_x; gemm3+gemm4 fused into k_head
// (kills g1 round-trip); 13 -> 10 dispatches.
// (R13 bench was an infra failure -- container died; resubmitting unchanged.)

#define NN 100000
#define NE 1600000
#define NG 512
#define NBLK ((NN + 1023) / 1024)   // 98 scan blocks

typedef float v2f __attribute__((ext_vector_type(2)));

// ---------------- CSR build (counting sort by dst) ----------------

__global__ void k_hist(const int* __restrict__ dst, int* cnt, int e) {
    int i = blockIdx.x * blockDim.x + threadIdx.x;
    if (i < e) atomicAdd(&cnt[dst[i]], 1);
}

// x [NN][78] fp32 -> xh fp16 ; also zero gmax (NG*256 = 131072 < NN*39)
__global__ void k_cvt_x(const float* __restrict__ x, __half* __restrict__ xh,
                        float* __restrict__ gmax) {
    int i = blockIdx.x * blockDim.x + threadIdx.x;
    if (i < NN * 39) {
        float2 v = ((const float2*)x)[i];
        ((__half2*)xh)[i] = __floats2half2_rn(v.x, v.y);
    }
    if (i < NG * 256) gmax[i] = 0.0f;
}

// block sums of cnt + dinv computation (reads cnt anyway)
__global__ __launch_bounds__(256) void k_bsum(const int* __restrict__ cnt,
    int* __restrict__ bsum, float* __restrict__ dinv) {
    __shared__ int s[256];
    int b = blockIdx.x, t = threadIdx.x;
    int base = b * 1024 + t * 4;
    int v = 0;
#pragma unroll
    for (int j = 0; j < 4; j++) {
        int i = base + j;
        if (i < NN) {
            int c = cnt[i];
            v += c;
            dinv[i] = rsqrtf((float)c + 1.0f);
        }
    }
    s[t] = v; __syncthreads();
    for (int off = 128; off > 0; off >>= 1) {
        if (t < off) s[t] += s[t + off];
        __syncthreads();
    }
    if (t == 0) bsum[b] = s[0];
}

__global__ __launch_bounds__(128) void k_scan_bsum(int* bsum, int* row_ptr) {
    __shared__ int s[128];
    int t = threadIdx.x;
    int v = (t < NBLK) ? bsum[t] : 0;
    s[t] = v; __syncthreads();
    for (int off = 1; off < 128; off <<= 1) {
        int u = (t >= off) ? s[t - off] : 0;
        __syncthreads();
        s[t] += u;
        __syncthreads();
    }
    if (t < NBLK) bsum[t] = s[t] - v;
    if (t == 0) row_ptr[NN] = NE;
}

__global__ __launch_bounds__(256) void k_scan_blocks(const int* __restrict__ cnt,
    const int* __restrict__ bsum, int* __restrict__ row_ptr, int* __restrict__ cursor) {
    __shared__ int s[256];
    int b = blockIdx.x, t = threadIdx.x;
    int base = b * 1024 + t * 4;
    int v[4]; int sum = 0;
#pragma unroll
    for (int j = 0; j < 4; j++) { int i = base + j; v[j] = (i < NN) ? cnt[i] : 0; sum += v[j]; }
    s[t] = sum; __syncthreads();
    for (int off = 1; off < 256; off <<= 1) {
        int u = (t >= off) ? s[t - off] : 0;
        __syncthreads();
        s[t] += u;
        __syncthreads();
    }
    int excl = s[t] - sum + bsum[b];
#pragma unroll
    for (int j = 0; j < 4; j++) {
        int i = base + j;
        if (i < NN) { row_ptr[i] = excl; cursor[i] = excl; excl += v[j]; }
    }
}

__global__ void k_fillslots(const int* __restrict__ src, const int* __restrict__ dst,
    const float* __restrict__ dinv, int* cursor, int2* __restrict__ es, int e) {
    int i = blockIdx.x * blockDim.x + threadIdx.x;
    if (i >= e) return;
    int s = src[i], d = dst[i];
    int pos = atomicAdd(&cursor[d], 1);
    es[pos] = make_int2(s, __float_as_int(dinv[s] * dinv[d]));
}

// ---------------- fused1: balanced pair-zip fp16 gather78 + fp32 gemm1 -> fp16 h1 ----------------
__global__ __launch_bounds__(256) void k_fused1(const __half* __restrict__ x,
    const int* __restrict__ rp, const int2* __restrict__ es,
    const float* __restrict__ dinv, const float* __restrict__ W,
    const float* __restrict__ bias, __half* __restrict__ out) {
    __shared__ float As[4][8][80];   // 10 KB
    int tid = threadIdx.x;
    int wv = tid >> 6, l = tid & 63;
    int task = __builtin_amdgcn_readfirstlane(blockIdx.x * 4 + wv);  // 12500 tasks
    int n0 = task * 8;

    // degree-balanced pairing: sort local indices by degree (uniform values)
    int deg[8], idx[8];
    {
        int e0 = rp[n0], ei;
#pragma unroll
        for (int i = 0; i < 8; i++) {
            ei = rp[n0 + i + 1];
            deg[i] = ei - e0; e0 = ei; idx[i] = i;
        }
    }
#pragma unroll
    for (int i = 1; i < 8; i++) {
        int dv = deg[i], iv = idx[i], j = i - 1;
        while (j >= 0 && deg[j] > dv) {
            deg[j + 1] = deg[j]; idx[j + 1] = idx[j]; j--;
        }
        deg[j + 1] = dv; idx[j + 1] = iv;
    }

    if (l < 39) {
        for (int pi = 0; pi < 4; pi++) {
            int iA = idx[2 * pi], iB = idx[2 * pi + 1];
            int nA = n0 + iA, nB = n0 + iB;
            float diA = dinv[nA], swA = diA * diA;
            float diB = dinv[nB], swB = diB * diB;
            float2 aA = __half22float2(((const __half2*)(x + (size_t)nA * 78))[l]);
            float2 aB = __half22float2(((const __half2*)(x + (size_t)nB * 78))[l]);
            aA.x *= swA; aA.y *= swA;
            aB.x *= swB; aB.y *= swB;
            int eA = rp[nA], eA1 = rp[nA + 1];
            int eB = rp[nB], eB1 = rp[nB + 1];
            int cA = (eA1 - eA) >> 3, cB = (eB1 - eB) >> 3;
            while (cA > 0 || cB > 0) {
                bool dA = (cA > 0), dB = (cB > 0);
                int2 esA[8], esB[8];
                __half2 vA[8], vB[8];
                if (dA) {
#pragma unroll
                    for (int j = 0; j < 8; j++) esA[j] = es[eA + j];
                }
                if (dB) {
#pragma unroll
                    for (int j = 0; j < 8; j++) esB[j] = es[eB + j];
                }
                if (dA) {
#pragma unroll
                    for (int j = 0; j < 8; j++)
                        vA[j] = ((const __half2*)(x + (size_t)esA[j].x * 78))[l];
                }
                if (dB) {
#pragma unroll
                    for (int j = 0; j < 8; j++)
                        vB[j] = ((const __half2*)(x + (size_t)esB[j].x * 78))[l];
                }
                if (dA) {
#pragma unroll
                    for (int j = 0; j < 8; j++) {
                        float w = __int_as_float(esA[j].y);
                        float2 v = __half22float2(vA[j]);
                        aA.x += v.x * w; aA.y += v.y * w;
                    }
                    eA += 8; cA--;
                }
                if (dB) {
#pragma unroll
                    for (int j = 0; j < 8; j++) {
                        float w = __int_as_float(esB[j].y);
                        float2 v = __half22float2(vB[j]);
                        aB.x += v.x * w; aB.y += v.y * w;
                    }
                    eB += 8; cB--;
                }
            }
            while (eA < eA1 && eB < eB1) {
                int2 pA = es[eA], pB = es[eB];
                float2 vA2 = __half22float2(((const __half2*)(x + (size_t)pA.x * 78))[l]);
                float2 vB2 = __half22float2(((const __half2*)(x + (size_t)pB.x * 78))[l]);
                float wA = __int_as_float(pA.y), wB = __int_as_float(pB.y);
                aA.x += vA2.x * wA; aA.y += vA2.y * wA;
                aB.x += vB2.x * wB; aB.y += vB2.y * wB;
                eA++; eB++;
            }
            for (; eA < eA1; eA++) {
                int2 p = es[eA];
                float w = __int_as_float(p.y);
                float2 v = __half22float2(((const __half2*)(x + (size_t)p.x * 78))[l]);
                aA.x += v.x * w; aA.y += v.y * w;
            }
            for (; eB < eB1; eB++) {
                int2 p = es[eB];
                float w = __int_as_float(p.y);
                float2 v = __half22float2(((const __half2*)(x + (size_t)p.x * 78))[l]);
                aB.x += v.x * w; aB.y += v.y * w;
            }
            *(float2*)&As[wv][iA][2 * l] = aA;
            *(float2*)&As[wv][iB][2 * l] = aB;
        }
    }
    // align the block's 4 waves so their (identical) GEMM W-streams share L1
    __syncthreads();

    int f0 = l * 2;
    float2 acc[8];
#pragma unroll
    for (int i = 0; i < 8; i++) acc[i] = make_float2(0.f, 0.f);

    for (int k = 0; k < 76; k += 4) {
        float2 w0 = *(const float2*)&W[(k + 0) * 128 + f0];
        float2 w1 = *(const float2*)&W[(k + 1) * 128 + f0];
        float2 w2 = *(const float2*)&W[(k + 2) * 128 + f0];
        float2 w3 = *(const float2*)&W[(k + 3) * 128 + f0];
#pragma unroll
        for (int i = 0; i < 8; i++) {
            float4 a = *(const float4*)&As[wv][i][k];
            acc[i].x += a.x * w0.x + a.y * w1.x + a.z * w2.x + a.w * w3.x;
            acc[i].y += a.x * w0.y + a.y * w1.y + a.z * w2.y + a.w * w3.y;
        }
    }
    {   // rows 76,77
        float2 w0 = *(const float2*)&W[76 * 128 + f0];
        float2 w1 = *(const float2*)&W[77 * 128 + f0];
#pragma unroll
        for (int i = 0; i < 8; i++) {
            float2 a = *(const float2*)&As[wv][i][76];
            acc[i].x += a.x * w0.x + a.y * w1.x;
            acc[i].y += a.x * w0.y + a.y * w1.y;
        }
    }
    float2 bv = *(const float2*)&bias[f0];
#pragma unroll
    for (int i = 0; i < 8; i++) {
        float ox = fmaxf(acc[i].x + bv.x, 0.f);
        float oy = fmaxf(acc[i].y + bv.y, 0.f);
        *(__half2*)&out[(size_t)(n0 + i) * 128 + f0] = __floats2half2_rn(ox, oy);
    }
}

// ---------------- fused2: balanced pair-zip fp16 gather128 + gemm2(pk_fma) + pool ----------------
__global__ __launch_bounds__(256) void k_fused2(const __half* __restrict__ h,
    const int* __restrict__ rp, const int2* __restrict__ es,
    const float* __restrict__ dinv, const float* __restrict__ W,
    const float* __restrict__ bias, const int* __restrict__ batch,
    unsigned* __restrict__ gmax) {
    __shared__ float As[4][8][128];  // 16 KB
    int tid = threadIdx.x;
    int wv = tid >> 6, l = tid & 63;
    int task = __builtin_amdgcn_readfirstlane(blockIdx.x * 4 + wv);  // 12500 tasks
    int n0 = task * 8;

    // degree-balanced pairing (uniform scalar sort)
    int deg[8], idx[8];
    {
        int e0 = rp[n0], ei;
#pragma unroll
        for (int i = 0; i < 8; i++) {
            ei = rp[n0 + i + 1];
            deg[i] = ei - e0; e0 = ei; idx[i] = i;
        }
    }
#pragma unroll
    for (int i = 1; i < 8; i++) {
        int dv = deg[i], iv = idx[i], j = i - 1;
        while (j >= 0 && deg[j] > dv) {
            deg[j + 1] = deg[j]; idx[j + 1] = idx[j]; j--;
        }
        deg[j + 1] = dv; idx[j + 1] = iv;
    }

    for (int pi = 0; pi < 4; pi++) {
        int iA = idx[2 * pi], iB = idx[2 * pi + 1];
        int nA = n0 + iA, nB = n0 + iB;
        float diA = dinv[nA], swA = diA * diA;
        float diB = dinv[nB], swB = diB * diB;
        float2 aA = __half22float2(((const __half2*)(h + (size_t)nA * 128))[l]);
        float2 aB = __half22float2(((const __half2*)(h + (size_t)nB * 128))[l]);
        aA.x *= swA; aA.y *= swA;
        aB.x *= swB; aB.y *= swB;
        int eA = rp[nA], eA1 = rp[nA + 1];
        int eB = rp[nB], eB1 = rp[nB + 1];
        int cA = (eA1 - eA) >> 3, cB = (eB1 - eB) >> 3;
        while (cA > 0 || cB > 0) {
            bool dA = (cA > 0), dB = (cB > 0);
            int2 esA[8], esB[8];
            __half2 vA[8], vB[8];
            if (dA) {
#pragma unroll
                for (int j = 0; j < 8; j++) esA[j] = es[eA + j];
            }
            if (dB) {
#pragma unroll
                for (int j = 0; j < 8; j++) esB[j] = es[eB + j];
            }
            if (dA) {
#pragma unroll
                for (int j = 0; j < 8; j++)
                    vA[j] = ((const __half2*)(h + (size_t)esA[j].x * 128))[l];
            }
            if (dB) {
#pragma unroll
                for (int j = 0; j < 8; j++)
                    vB[j] = ((const __half2*)(h + (size_t)esB[j].x * 128))[l];
            }
            if (dA) {
#pragma unroll
                for (int j = 0; j < 8; j++) {
                    float w = __int_as_float(esA[j].y);
                    float2 v = __half22float2(vA[j]);
                    aA.x += v.x * w; aA.y += v.y * w;
                }
                eA += 8; cA--;
            }
            if (dB) {
#pragma unroll
                for (int j = 0; j < 8; j++) {
                    float w = __int_as_float(esB[j].y);
                    float2 v = __half22float2(vB[j]);
                    aB.x += v.x * w; aB.y += v.y * w;
                }
                eB += 8; cB--;
            }
        }
        while (eA < eA1 && eB < eB1) {
            int2 pA = es[eA], pB = es[eB];
            float2 vA2 = __half22float2(((const __half2*)(h + (size_t)pA.x * 128))[l]);
            float2 vB2 = __half22float2(((const __half2*)(h + (size_t)pB.x * 128))[l]);
            float wA = __int_as_float(pA.y), wB = __int_as_float(pB.y);
            aA.x += vA2.x * wA; aA.y += vA2.y * wA;
            aB.x += vB2.x * wB; aB.y += vB2.y * wB;
            eA++; eB++;
        }
        for (; eA < eA1; eA++) {
            int2 p = es[eA];
            float w = __int_as_float(p.y);
            float2 v = __half22float2(((const __half2*)(h + (size_t)p.x * 128))[l]);
            aA.x += v.x * w; aA.y += v.y * w;
        }
        for (; eB < eB1; eB++) {
            int2 p = es[eB];
            float w = __int_as_float(p.y);
            float2 v = __half22float2(((const __half2*)(h + (size_t)p.x * 128))[l]);
            aB.x += v.x * w; aB.y += v.y * w;
        }
        *(float2*)&As[wv][iA][2 * l] = aA;
        *(float2*)&As[wv][iB][2 * l] = aB;
    }
    // align the block's 4 waves so their (identical) GEMM W-streams share L1
    __syncthreads();

    int f0 = l * 4;
    v2f acc[8][2];
#pragma unroll
    for (int i = 0; i < 8; i++) { acc[i][0] = (v2f)(0.f); acc[i][1] = (v2f)(0.f); }

    for (int k = 0; k < 128; k += 4) {
        float4 w0 = *(const float4*)&W[(size_t)(k + 0) * 256 + f0];
        float4 w1 = *(const float4*)&W[(size_t)(k + 1) * 256 + f0];
        float4 w2 = *(const float4*)&W[(size_t)(k + 2) * 256 + f0];
        float4 w3 = *(const float4*)&W[(size_t)(k + 3) * 256 + f0];
        v2f w0a = {w0.x, w0.y}, w0b = {w0.z, w0.w};
        v2f w1a = {w1.x, w1.y}, w1b = {w1.z, w1.w};
        v2f w2a = {w2.x, w2.y}, w2b = {w2.z, w2.w};
        v2f w3a = {w3.x, w3.y}, w3b = {w3.z, w3.w};
#pragma unroll
        for (int i = 0; i < 8; i++) {
            float4 a = *(const float4*)&As[wv][i][k];
            v2f sx = {a.x, a.x}, sy = {a.y, a.y}, sz = {a.z, a.z}, sw = {a.w, a.w};
            acc[i][0] = __builtin_elementwise_fma(sx, w0a, acc[i][0]);
            acc[i][1] = __builtin_elementwise_fma(sx, w0b, acc[i][1]);
            acc[i][0] = __builtin_elementwise_fma(sy, w1a, acc[i][0]);
            acc[i][1] = __builtin_elementwise_fma(sy, w1b, acc[i][1]);
            acc[i][0] = __builtin_elementwise_fma(sz, w2a, acc[i][0]);
            acc[i][1] = __builtin_elementwise_fma(sz, w2b, acc[i][1]);
            acc[i][0] = __builtin_elementwise_fma(sw, w3a, acc[i][0]);
            acc[i][1] = __builtin_elementwise_fma(sw, w3b, acc[i][1]);
        }
    }

    float4 bv = *(const float4*)&bias[f0];
    int curg = -1;
    float4 m = make_float4(0.f, 0.f, 0.f, 0.f);
#pragma unroll
    for (int i = 0; i < 8; i++) {
        int g = batch[n0 + i];
        float4 v;
        v.x = fmaxf(acc[i][0].x + bv.x, 0.f); v.y = fmaxf(acc[i][0].y + bv.y, 0.f);
        v.z = fmaxf(acc[i][1].x + bv.z, 0.f); v.w = fmaxf(acc[i][1].y + bv.w, 0.f);
        if (g != curg) {
            if (curg >= 0) {
                unsigned* gp = &gmax[(size_t)curg * 256 + f0];
                atomicMax(&gp[0], __float_as_uint(m.x));
                atomicMax(&gp[1], __float_as_uint(m.y));
                atomicMax(&gp[2], __float_as_uint(m.z));
                atomicMax(&gp[3], __float_as_uint(m.w));
            }
            curg = g; m = v;
        } else {
            m.x = fmaxf(m.x, v.x); m.y = fmaxf(m.y, v.y);
            m.z = fmaxf(m.z, v.z); m.w = fmaxf(m.w, v.w);
        }
    }
    if (curg >= 0) {
        unsigned* gp = &gmax[(size_t)curg * 256 + f0];
        atomicMax(&gp[0], __float_as_uint(m.x));
        atomicMax(&gp[1], __float_as_uint(m.y));
        atomicMax(&gp[2], __float_as_uint(m.z));
        atomicMax(&gp[3], __float_as_uint(m.w));
    }
}

// ---------------- MLP head (fused gemm3+gemm4, 8 graphs/block, 64 blocks) ----------------
__global__ __launch_bounds__(256) void k_head(const float* __restrict__ A,
    const float* __restrict__ Wg1, const float* __restrict__ bg1,
    const float* __restrict__ Wg2, const float* __restrict__ bg2,
    float* __restrict__ out) {
    __shared__ float rs[8][256];     // 8 KB
    __shared__ float g1s[8][1024];   // 32 KB
    int b = blockIdx.x, tid = threadIdx.x;
#pragma unroll
    for (int g = 0; g < 8; g++) rs[g][tid] = A[(b * 8 + g) * 256 + tid];
    __syncthreads();
    float acc[8][4];
#pragma unroll
    for (int g = 0; g < 8; g++)
#pragma unroll
        for (int j = 0; j < 4; j++) acc[g][j] = 0.f;
    for (int k = 0; k < 256; k++) {
        float w0 = Wg1[k * 1024 + tid];
        float w1 = Wg1[k * 1024 + tid + 256];
        float w2 = Wg1[k * 1024 + tid + 512];
        float w3 = Wg1[k * 1024 + tid + 768];
#pragma unroll
        for (int g = 0; g < 8; g++) {
            float a = rs[g][k];
            acc[g][0] += a * w0; acc[g][1] += a * w1;
            acc[g][2] += a * w2; acc[g][3] += a * w3;
        }
    }
#pragma unroll
    for (int g = 0; g < 8; g++)
#pragma unroll
        for (int j = 0; j < 4; j++) {
            int f = tid + j * 256;
            g1s[g][f] = fmaxf(acc[g][j] + bg1[f], 0.0f);
        }
    __syncthreads();
    // gemm4: 8 graphs x 128 feats; thread covers (grp*4..+3, f)
    int f = tid & 127, grp = tid >> 7;
    float o[4] = {0.f, 0.f, 0.f, 0.f};
    for (int k = 0; k < 1024; k++) {
        float w = Wg2[k * 128 + f];
#pragma unroll
        for (int t = 0; t < 4; t++) o[t] += g1s[grp * 4 + t][k] * w;
    }
    float bb = bg2[f];
#pragma unroll
    for (int t = 0; t < 4; t++)
        out[(size_t)(b * 8 + grp * 4 + t) * 128 + f] = o[t] + bb;
}

extern "C" void kernel_launch(void* const* d_in, const int* in_sizes, int n_in,
                              void* d_out, int out_size, void* d_ws, size_t ws_size,
                              hipStream_t stream) {
    const float* x    = (const float*)d_in[0];
    const int*   ei   = (const int*)d_in[1];
    const int*   batch= (const int*)d_in[2];
    const float* W1   = (const float*)d_in[3];
    const float* b1   = (const float*)d_in[4];
    const float* W2   = (const float*)d_in[5];
    const float* b2   = (const float*)d_in[6];
    const float* Wg1  = (const float*)d_in[7];
    const float* bg1  = (const float*)d_in[8];
    const float* Wg2  = (const float*)d_in[9];
    const float* bg2  = (const float*)d_in[10];
    const int* src = ei;
    const int* dst = ei + NE;

    char* w8 = (char*)d_ws;
    int*   cnt     = (int*)w8;                 w8 += (size_t)NN * 4;
    int*   row_ptr = (int*)w8;                 w8 += (size_t)(NN + 4) * 4;
    int*   cursor  = (int*)w8;                 w8 += (size_t)NN * 4;
    int*   bsum    = (int*)w8;                 w8 += 128 * 4;
    int2*  es      = (int2*)w8;                w8 += (size_t)NE * 8;
    float* dinv    = (float*)w8;               w8 += (size_t)NN * 4;
    __half* xh     = (__half*)w8;              w8 += (size_t)NN * 78 * 2;
    __half* h1     = (__half*)w8;              w8 += (size_t)NN * 128 * 2;
    unsigned* gmax = (unsigned*)w8;            w8 += (size_t)NG * 256 * 4;

    // CSR build + x conversion (dinv folded into k_bsum; gmax zero into k_cvt_x)
    hipMemsetAsync(cnt, 0, (size_t)NN * 4, stream);
    k_hist<<<(NE + 255) / 256, 256, 0, stream>>>(dst, cnt, NE);
    k_cvt_x<<<(NN * 39 + 255) / 256, 256, 0, stream>>>(x, xh, (float*)gmax);
    k_bsum<<<NBLK, 256, 0, stream>>>(cnt, bsum, dinv);
    k_scan_bsum<<<1, 128, 0, stream>>>(bsum, row_ptr);
    k_scan_blocks<<<NBLK, 256, 0, stream>>>(cnt, bsum, row_ptr, cursor);
    k_fillslots<<<(NE + 255) / 256, 256, 0, stream>>>(src, dst, dinv, cursor, es, NE);

    // layer 1 (fused balanced pair-zip fp16 gather + fp32 gemm + relu -> fp16 h1)
    k_fused1<<<NN / 32, 256, 0, stream>>>(xh, row_ptr, es, dinv, W1, b1, h1);

    // layer 2 (fused balanced pair-zip fp16 gather + gemm + relu + pool)
    k_fused2<<<NN / 32, 256, 0, stream>>>(h1, row_ptr, es, dinv, W2, b2, batch, gmax);

    // MLP head (gemm3+gemm4 fused)
    k_head<<<NG / 8, 256, 0, stream>>>((const float*)gmax, Wg1, bg1, Wg2, bg2, (float*)d_out);
}

// Round 15
// 555.598 us; speedup vs baseline: 1.0776x; 1.0290x over previous
//
#include <hip/hip_runtime.h>
#include <hip/hip_fp16.h>

// GCN forward, CSR-gather, fused gather+GEMM (R11 structure: balanced
// pair-zip, 4 waves/block, 8 nodes/wave, fp16 gather traffic, VGPR-lean 40).
// R14 falsified the lockstep-L1 theory (GEMM phase is VALU-issue-bound, 84%
// VALU mix; barrier only added straggler cost) -> syncthreads removed.
// Kept: fused MLP head (no g1 round-trip), k_prep folded into k_bsum/cvt.
// NEW: k_hist + k_cvt_x + gmax-zero fused into ONE kernel (independent
// elementwise work; cvt's 46MB stream overlaps hist's atomic latency).
// 9 dispatches total.

#define NN 100000
#define NE 1600000
#define NG 512
#define NBLK ((NN + 1023) / 1024)   // 98 scan blocks

typedef float v2f __attribute__((ext_vector_type(2)));

// ---------------- CSR build (counting sort by dst) ----------------

// fused: edge histogram + x fp32->fp16 conversion + gmax zero-init
__global__ void k_hist_cvt(const int* __restrict__ dst, int* cnt,
                           const float* __restrict__ x, __half* __restrict__ xh,
                           float* __restrict__ gmax) {
    int i = blockIdx.x * blockDim.x + threadIdx.x;
    if (i < NE) atomicAdd(&cnt[dst[i]], 1);
    if (i < NN * 39) {
        float2 v = ((const float2*)x)[i];
        ((__half2*)xh)[i] = __floats2half2_rn(v.x, v.y);
    }
    if (i < NG * 256) gmax[i] = 0.0f;
}

// block sums of cnt + dinv computation (reads cnt anyway)
__global__ __launch_bounds__(256) void k_bsum(const int* __restrict__ cnt,
    int* __restrict__ bsum, float* __restrict__ dinv) {
    __shared__ int s[256];
    int b = blockIdx.x, t = threadIdx.x;
    int base = b * 1024 + t * 4;
    int v = 0;
#pragma unroll
    for (int j = 0; j < 4; j++) {
        int i = base + j;
        if (i < NN) {
            int c = cnt[i];
            v += c;
            dinv[i] = rsqrtf((float)c + 1.0f);
        }
    }
    s[t] = v; __syncthreads();
    for (int off = 128; off > 0; off >>= 1) {
        if (t < off) s[t] += s[t + off];
        __syncthreads();
    }
    if (t == 0) bsum[b] = s[0];
}

__global__ __launch_bounds__(128) void k_scan_bsum(int* bsum, int* row_ptr) {
    __shared__ int s[128];
    int t = threadIdx.x;
    int v = (t < NBLK) ? bsum[t] : 0;
    s[t] = v; __syncthreads();
    for (int off = 1; off < 128; off <<= 1) {
        int u = (t >= off) ? s[t - off] : 0;
        __syncthreads();
        s[t] += u;
        __syncthreads();
    }
    if (t < NBLK) bsum[t] = s[t] - v;
    if (t == 0) row_ptr[NN] = NE;
}

__global__ __launch_bounds__(256) void k_scan_blocks(const int* __restrict__ cnt,
    const int* __restrict__ bsum, int* __restrict__ row_ptr, int* __restrict__ cursor) {
    __shared__ int s[256];
    int b = blockIdx.x, t = threadIdx.x;
    int base = b * 1024 + t * 4;
    int v[4]; int sum = 0;
#pragma unroll
    for (int j = 0; j < 4; j++) { int i = base + j; v[j] = (i < NN) ? cnt[i] : 0; sum += v[j]; }
    s[t] = sum; __syncthreads();
    for (int off = 1; off < 256; off <<= 1) {
        int u = (t >= off) ? s[t - off] : 0;
        __syncthreads();
        s[t] += u;
        __syncthreads();
    }
    int excl = s[t] - sum + bsum[b];
#pragma unroll
    for (int j = 0; j < 4; j++) {
        int i = base + j;
        if (i < NN) { row_ptr[i] = excl; cursor[i] = excl; excl += v[j]; }
    }
}

__global__ void k_fillslots(const int* __restrict__ src, const int* __restrict__ dst,
    const float* __restrict__ dinv, int* cursor, int2* __restrict__ es, int e) {
    int i = blockIdx.x * blockDim.x + threadIdx.x;
    if (i >= e) return;
    int s = src[i], d = dst[i];
    int pos = atomicAdd(&cursor[d], 1);
    es[pos] = make_int2(s, __float_as_int(dinv[s] * dinv[d]));
}

// ---------------- fused1: balanced pair-zip fp16 gather78 + fp32 gemm1 -> fp16 h1 ----------------
__global__ __launch_bounds__(256) void k_fused1(const __half* __restrict__ x,
    const int* __restrict__ rp, const int2* __restrict__ es,
    const float* __restrict__ dinv, const float* __restrict__ W,
    const float* __restrict__ bias, __half* __restrict__ out) {
    __shared__ float As[4][8][80];   // 10 KB
    int tid = threadIdx.x;
    int wv = tid >> 6, l = tid & 63;
    int task = __builtin_amdgcn_readfirstlane(blockIdx.x * 4 + wv);  // 12500 tasks
    int n0 = task * 8;

    // degree-balanced pairing: sort local indices by degree (uniform values)
    int deg[8], idx[8];
    {
        int e0 = rp[n0], ei;
#pragma unroll
        for (int i = 0; i < 8; i++) {
            ei = rp[n0 + i + 1];
            deg[i] = ei - e0; e0 = ei; idx[i] = i;
        }
    }
#pragma unroll
    for (int i = 1; i < 8; i++) {
        int dv = deg[i], iv = idx[i], j = i - 1;
        while (j >= 0 && deg[j] > dv) {
            deg[j + 1] = deg[j]; idx[j + 1] = idx[j]; j--;
        }
        deg[j + 1] = dv; idx[j + 1] = iv;
    }

    if (l < 39) {
        for (int pi = 0; pi < 4; pi++) {
            int iA = idx[2 * pi], iB = idx[2 * pi + 1];
            int nA = n0 + iA, nB = n0 + iB;
            float diA = dinv[nA], swA = diA * diA;
            float diB = dinv[nB], swB = diB * diB;
            float2 aA = __half22float2(((const __half2*)(x + (size_t)nA * 78))[l]);
            float2 aB = __half22float2(((const __half2*)(x + (size_t)nB * 78))[l]);
            aA.x *= swA; aA.y *= swA;
            aB.x *= swB; aB.y *= swB;
            int eA = rp[nA], eA1 = rp[nA + 1];
            int eB = rp[nB], eB1 = rp[nB + 1];
            int cA = (eA1 - eA) >> 3, cB = (eB1 - eB) >> 3;
            while (cA > 0 || cB > 0) {
                bool dA = (cA > 0), dB = (cB > 0);
                int2 esA[8], esB[8];
                __half2 vA[8], vB[8];
                if (dA) {
#pragma unroll
                    for (int j = 0; j < 8; j++) esA[j] = es[eA + j];
                }
                if (dB) {
#pragma unroll
                    for (int j = 0; j < 8; j++) esB[j] = es[eB + j];
                }
                if (dA) {
#pragma unroll
                    for (int j = 0; j < 8; j++)
                        vA[j] = ((const __half2*)(x + (size_t)esA[j].x * 78))[l];
                }
                if (dB) {
#pragma unroll
                    for (int j = 0; j < 8; j++)
                        vB[j] = ((const __half2*)(x + (size_t)esB[j].x * 78))[l];
                }
                if (dA) {
#pragma unroll
                    for (int j = 0; j < 8; j++) {
                        float w = __int_as_float(esA[j].y);
                        float2 v = __half22float2(vA[j]);
                        aA.x += v.x * w; aA.y += v.y * w;
                    }
                    eA += 8; cA--;
                }
                if (dB) {
#pragma unroll
                    for (int j = 0; j < 8; j++) {
                        float w = __int_as_float(esB[j].y);
                        float2 v = __half22float2(vB[j]);
                        aB.x += v.x * w; aB.y += v.y * w;
                    }
                    eB += 8; cB--;
                }
            }
            while (eA < eA1 && eB < eB1) {
                int2 pA = es[eA], pB = es[eB];
                float2 vA2 = __half22float2(((const __half2*)(x + (size_t)pA.x * 78))[l]);
                float2 vB2 = __half22float2(((const __half2*)(x + (size_t)pB.x * 78))[l]);
                float wA = __int_as_float(pA.y), wB = __int_as_float(pB.y);
                aA.x += vA2.x * wA; aA.y += vA2.y * wA;
                aB.x += vB2.x * wB; aB.y += vB2.y * wB;
                eA++; eB++;
            }
            for (; eA < eA1; eA++) {
                int2 p = es[eA];
                float w = __int_as_float(p.y);
                float2 v = __half22float2(((const __half2*)(x + (size_t)p.x * 78))[l]);
                aA.x += v.x * w; aA.y += v.y * w;
            }
            for (; eB < eB1; eB++) {
                int2 p = es[eB];
                float w = __int_as_float(p.y);
                float2 v = __half22float2(((const __half2*)(x + (size_t)p.x * 78))[l]);
                aB.x += v.x * w; aB.y += v.y * w;
            }
            *(float2*)&As[wv][iA][2 * l] = aA;
            *(float2*)&As[wv][iB][2 * l] = aB;
        }
    }
    // same-wave producer/consumer: lgkmcnt ordering, no barrier (R14: barrier hurt).

    int f0 = l * 2;
    float2 acc[8];
#pragma unroll
    for (int i = 0; i < 8; i++) acc[i] = make_float2(0.f, 0.f);

    for (int k = 0; k < 76; k += 4) {
        float2 w0 = *(const float2*)&W[(k + 0) * 128 + f0];
        float2 w1 = *(const float2*)&W[(k + 1) * 128 + f0];
        float2 w2 = *(const float2*)&W[(k + 2) * 128 + f0];
        float2 w3 = *(const float2*)&W[(k + 3) * 128 + f0];
#pragma unroll
        for (int i = 0; i < 8; i++) {
            float4 a = *(const float4*)&As[wv][i][k];
            acc[i].x += a.x * w0.x + a.y * w1.x + a.z * w2.x + a.w * w3.x;
            acc[i].y += a.x * w0.y + a.y * w1.y + a.z * w2.y + a.w * w3.y;
        }
    }
    {   // rows 76,77
        float2 w0 = *(const float2*)&W[76 * 128 + f0];
        float2 w1 = *(const float2*)&W[77 * 128 + f0];
#pragma unroll
        for (int i = 0; i < 8; i++) {
            float2 a = *(const float2*)&As[wv][i][76];
            acc[i].x += a.x * w0.x + a.y * w1.x;
            acc[i].y += a.x * w0.y + a.y * w1.y;
        }
    }
    float2 bv = *(const float2*)&bias[f0];
#pragma unroll
    for (int i = 0; i < 8; i++) {
        float ox = fmaxf(acc[i].x + bv.x, 0.f);
        float oy = fmaxf(acc[i].y + bv.y, 0.f);
        *(__half2*)&out[(size_t)(n0 + i) * 128 + f0] = __floats2half2_rn(ox, oy);
    }
}

// ---------------- fused2: balanced pair-zip fp16 gather128 + gemm2(pk_fma) + pool ----------------
__global__ __launch_bounds__(256) void k_fused2(const __half* __restrict__ h,
    const int* __restrict__ rp, const int2* __restrict__ es,
    const float* __restrict__ dinv, const float* __restrict__ W,
    const float* __restrict__ bias, const int* __restrict__ batch,
    unsigned* __restrict__ gmax) {
    __shared__ float As[4][8][128];  // 16 KB
    int tid = threadIdx.x;
    int wv = tid >> 6, l = tid & 63;
    int task = __builtin_amdgcn_readfirstlane(blockIdx.x * 4 + wv);  // 12500 tasks
    int n0 = task * 8;

    // degree-balanced pairing (uniform scalar sort)
    int deg[8], idx[8];
    {
        int e0 = rp[n0], ei;
#pragma unroll
        for (int i = 0; i < 8; i++) {
            ei = rp[n0 + i + 1];
            deg[i] = ei - e0; e0 = ei; idx[i] = i;
        }
    }
#pragma unroll
    for (int i = 1; i < 8; i++) {
        int dv = deg[i], iv = idx[i], j = i - 1;
        while (j >= 0 && deg[j] > dv) {
            deg[j + 1] = deg[j]; idx[j + 1] = idx[j]; j--;
        }
        deg[j + 1] = dv; idx[j + 1] = iv;
    }

    for (int pi = 0; pi < 4; pi++) {
        int iA = idx[2 * pi], iB = idx[2 * pi + 1];
        int nA = n0 + iA, nB = n0 + iB;
        float diA = dinv[nA], swA = diA * diA;
        float diB = dinv[nB], swB = diB * diB;
        float2 aA = __half22float2(((const __half2*)(h + (size_t)nA * 128))[l]);
        float2 aB = __half22float2(((const __half2*)(h + (size_t)nB * 128))[l]);
        aA.x *= swA; aA.y *= swA;
        aB.x *= swB; aB.y *= swB;
        int eA = rp[nA], eA1 = rp[nA + 1];
        int eB = rp[nB], eB1 = rp[nB + 1];
        int cA = (eA1 - eA) >> 3, cB = (eB1 - eB) >> 3;
        while (cA > 0 || cB > 0) {
            bool dA = (cA > 0), dB = (cB > 0);
            int2 esA[8], esB[8];
            __half2 vA[8], vB[8];
            if (dA) {
#pragma unroll
                for (int j = 0; j < 8; j++) esA[j] = es[eA + j];
            }
            if (dB) {
#pragma unroll
                for (int j = 0; j < 8; j++) esB[j] = es[eB + j];
            }
            if (dA) {
#pragma unroll
                for (int j = 0; j < 8; j++)
                    vA[j] = ((const __half2*)(h + (size_t)esA[j].x * 128))[l];
            }
            if (dB) {
#pragma unroll
                for (int j = 0; j < 8; j++)
                    vB[j] = ((const __half2*)(h + (size_t)esB[j].x * 128))[l];
            }
            if (dA) {
#pragma unroll
                for (int j = 0; j < 8; j++) {
                    float w = __int_as_float(esA[j].y);
                    float2 v = __half22float2(vA[j]);
                    aA.x += v.x * w; aA.y += v.y * w;
                }
                eA += 8; cA--;
            }
            if (dB) {
#pragma unroll
                for (int j = 0; j < 8; j++) {
                    float w = __int_as_float(esB[j].y);
                    float2 v = __half22float2(vB[j]);
                    aB.x += v.x * w; aB.y += v.y * w;
                }
                eB += 8; cB--;
            }
        }
        while (eA < eA1 && eB < eB1) {
            int2 pA = es[eA], pB = es[eB];
            float2 vA2 = __half22float2(((const __half2*)(h + (size_t)pA.x * 128))[l]);
            float2 vB2 = __half22float2(((const __half2*)(h + (size_t)pB.x * 128))[l]);
            float wA = __int_as_float(pA.y), wB = __int_as_float(pB.y);
            aA.x += vA2.x * wA; aA.y += vA2.y * wA;
            aB.x += vB2.x * wB; aB.y += vB2.y * wB;
            eA++; eB++;
        }
        for (; eA < eA1; eA++) {
            int2 p = es[eA];
            float w = __int_as_float(p.y);
            float2 v = __half22float2(((const __half2*)(h + (size_t)p.x * 128))[l]);
            aA.x += v.x * w; aA.y += v.y * w;
        }
        for (; eB < eB1; eB++) {
            int2 p = es[eB];
            float w = __int_as_float(p.y);
            float2 v = __half22float2(((const __half2*)(h + (size_t)p.x * 128))[l]);
            aB.x += v.x * w; aB.y += v.y * w;
        }
        *(float2*)&As[wv][iA][2 * l] = aA;
        *(float2*)&As[wv][iB][2 * l] = aB;
    }
    // same-wave producer/consumer: no barrier (R14: barrier hurt).

    int f0 = l * 4;
    v2f acc[8][2];
#pragma unroll
    for (int i = 0; i < 8; i++) { acc[i][0] = (v2f)(0.f); acc[i][1] = (v2f)(0.f); }

    for (int k = 0; k < 128; k += 4) {
        float4 w0 = *(const float4*)&W[(size_t)(k + 0) * 256 + f0];
        float4 w1 = *(const float4*)&W[(size_t)(k + 1) * 256 + f0];
        float4 w2 = *(const float4*)&W[(size_t)(k + 2) * 256 + f0];
        float4 w3 = *(const float4*)&W[(size_t)(k + 3) * 256 + f0];
        v2f w0a = {w0.x, w0.y}, w0b = {w0.z, w0.w};
        v2f w1a = {w1.x, w1.y}, w1b = {w1.z, w1.w};
        v2f w2a = {w2.x, w2.y}, w2b = {w2.z, w2.w};
        v2f w3a = {w3.x, w3.y}, w3b = {w3.z, w3.w};
#pragma unroll
        for (int i = 0; i < 8; i++) {
            float4 a = *(const float4*)&As[wv][i][k];
            v2f sx = {a.x, a.x}, sy = {a.y, a.y}, sz = {a.z, a.z}, sw = {a.w, a.w};
            acc[i][0] = __builtin_elementwise_fma(sx, w0a, acc[i][0]);
            acc[i][1] = __builtin_elementwise_fma(sx, w0b, acc[i][1]);
            acc[i][0] = __builtin_elementwise_fma(sy, w1a, acc[i][0]);
            acc[i][1] = __builtin_elementwise_fma(sy, w1b, acc[i][1]);
            acc[i][0] = __builtin_elementwise_fma(sz, w2a, acc[i][0]);
            acc[i][1] = __builtin_elementwise_fma(sz, w2b, acc[i][1]);
            acc[i][0] = __builtin_elementwise_fma(sw, w3a, acc[i][0]);
            acc[i][1] = __builtin_elementwise_fma(sw, w3b, acc[i][1]);
        }
    }

    float4 bv = *(const float4*)&bias[f0];
    int curg = -1;
    float4 m = make_float4(0.f, 0.f, 0.f, 0.f);
#pragma unroll
    for (int i = 0; i < 8; i++) {
        int g = batch[n0 + i];
        float4 v;
        v.x = fmaxf(acc[i][0].x + bv.x, 0.f); v.y = fmaxf(acc[i][0].y + bv.y, 0.f);
        v.z = fmaxf(acc[i][1].x + bv.z, 0.f); v.w = fmaxf(acc[i][1].y + bv.w, 0.f);
        if (g != curg) {
            if (curg >= 0) {
                unsigned* gp = &gmax[(size_t)curg * 256 + f0];
                atomicMax(&gp[0], __float_as_uint(m.x));
                atomicMax(&gp[1], __float_as_uint(m.y));
                atomicMax(&gp[2], __float_as_uint(m.z));
                atomicMax(&gp[3], __float_as_uint(m.w));
            }
            curg = g; m = v;
        } else {
            m.x = fmaxf(m.x, v.x); m.y = fmaxf(m.y, v.y);
            m.z = fmaxf(m.z, v.z); m.w = fmaxf(m.w, v.w);
        }
    }
    if (curg >= 0) {
        unsigned* gp = &gmax[(size_t)curg * 256 + f0];
        atomicMax(&gp[0], __float_as_uint(m.x));
        atomicMax(&gp[1], __float_as_uint(m.y));
        atomicMax(&gp[2], __float_as_uint(m.z));
        atomicMax(&gp[3], __float_as_uint(m.w));
    }
}

// ---------------- MLP head (fused gemm3+gemm4, 8 graphs/block, 64 blocks) ----------------
__global__ __launch_bounds__(256) void k_head(const float* __restrict__ A,
    const float* __restrict__ Wg1, const float* __restrict__ bg1,
    const float* __restrict__ Wg2, const float* __restrict__ bg2,
    float* __restrict__ out) {
    __shared__ float rs[8][256];     // 8 KB
    __shared__ float g1s[8][1024];   // 32 KB
    int b = blockIdx.x, tid = threadIdx.x;
#pragma unroll
    for (int g = 0; g < 8; g++) rs[g][tid] = A[(b * 8 + g) * 256 + tid];
    __syncthreads();
    float acc[8][4];
#pragma unroll
    for (int g = 0; g < 8; g++)
#pragma unroll
        for (int j = 0; j < 4; j++) acc[g][j] = 0.f;
    for (int k = 0; k < 256; k++) {
        float w0 = Wg1[k * 1024 + tid];
        float w1 = Wg1[k * 1024 + tid + 256];
        float w2 = Wg1[k * 1024 + tid + 512];
        float w3 = Wg1[k * 1024 + tid + 768];
#pragma unroll
        for (int g = 0; g < 8; g++) {
            float a = rs[g][k];
            acc[g][0] += a * w0; acc[g][1] += a * w1;
            acc[g][2] += a * w2; acc[g][3] += a * w3;
        }
    }
#pragma unroll
    for (int g = 0; g < 8; g++)
#pragma unroll
        for (int j = 0; j < 4; j++) {
            int f = tid + j * 256;
            g1s[g][f] = fmaxf(acc[g][j] + bg1[f], 0.0f);
        }
    __syncthreads();
    // gemm4: 8 graphs x 128 feats; thread covers (grp*4..+3, f)
    int f = tid & 127, grp = tid >> 7;
    float o[4] = {0.f, 0.f, 0.f, 0.f};
    for (int k = 0; k < 1024; k++) {
        float w = Wg2[k * 128 + f];
#pragma unroll
        for (int t = 0; t < 4; t++) o[t] += g1s[grp * 4 + t][k] * w;
    }
    float bb = bg2[f];
#pragma unroll
    for (int t = 0; t < 4; t++)
        out[(size_t)(b * 8 + grp * 4 + t) * 128 + f] = o[t] + bb;
}

extern "C" void kernel_launch(void* const* d_in, const int* in_sizes, int n_in,
                              void* d_out, int out_size, void* d_ws, size_t ws_size,
                              hipStream_t stream) {
    const float* x    = (const float*)d_in[0];
    const int*   ei   = (const int*)d_in[1];
    const int*   batch= (const int*)d_in[2];
    const float* W1   = (const float*)d_in[3];
    const float* b1   = (const float*)d_in[4];
    const float* W2   = (const float*)d_in[5];
    const float* b2   = (const float*)d_in[6];
    const float* Wg1  = (const float*)d_in[7];
    const float* bg1  = (const float*)d_in[8];
    const float* Wg2  = (const float*)d_in[9];
    const float* bg2  = (const float*)d_in[10];
    const int* src = ei;
    const int* dst = ei + NE;

    char* w8 = (char*)d_ws;
    int*   cnt     = (int*)w8;                 w8 += (size_t)NN * 4;
    int*   row_ptr = (int*)w8;                 w8 += (size_t)(NN + 4) * 4;
    int*   cursor  = (int*)w8;                 w8 += (size_t)NN * 4;
    int*   bsum    = (int*)w8;                 w8 += 128 * 4;
    int2*  es      = (int2*)w8;                w8 += (size_t)NE * 8;
    float* dinv    = (float*)w8;               w8 += (size_t)NN * 4;
    __half* xh     = (__half*)w8;              w8 += (size_t)NN * 78 * 2;
    __half* h1     = (__half*)w8;              w8 += (size_t)NN * 128 * 2;
    unsigned* gmax = (unsigned*)w8;            w8 += (size_t)NG * 256 * 4;

    // CSR build + x conversion (hist/cvt/gmax-zero fused; dinv folded into bsum)
    hipMemsetAsync(cnt, 0, (size_t)NN * 4, stream);
    k_hist_cvt<<<(NN * 39 + 255) / 256, 256, 0, stream>>>(dst, cnt, x, xh, (float*)gmax);
    k_bsum<<<NBLK, 256, 0, stream>>>(cnt, bsum, dinv);
    k_scan_bsum<<<1, 128, 0, stream>>>(bsum, row_ptr);
    k_scan_blocks<<<NBLK, 256, 0, stream>>>(cnt, bsum, row_ptr, cursor);
    k_fillslots<<<(NE + 255) / 256, 256, 0, stream>>>(src, dst, dinv, cursor, es, NE);

    // layer 1 (fused balanced pair-zip fp16 gather + fp32 gemm + relu -> fp16 h1)
    k_fused1<<<NN / 32, 256, 0, stream>>>(xh, row_ptr, es, dinv, W1, b1, h1);

    // layer 2 (fused balanced pair-zip fp16 gather + gemm + relu + pool)
    k_fused2<<<NN / 32, 256, 0, stream>>>(h1, row_ptr, es, dinv, W2, b2, batch, gmax);

    // MLP head (gemm3+gemm4 fused)
    k_head<<<NG / 8, 256, 0, stream>>>((const float*)gmax, Wg1, bg1, Wg2, bg2, (float*)d_out);
}